// Round 1
// baseline (494.992 us; speedup 1.0000x reference)
//
#include <hip/hip_runtime.h>
#include <math.h>

#define NCH 4096          // channel count (images)
#define IMG 64            // image side
#define HW  (IMG * IMG)   // 4096 pixels per image
#define NM  4             // number of multiplier kernels
#define TPAD 65           // LDS row stride: 65 -> stencil reads are 2-way bank aliasing (free)

__device__ __forceinline__ void atomicMaxF(float* addr, float v) {
    // Works for mixed signs given init = -inf:
    //  - positive v: int-compare max (negative floats have negative int bits)
    //  - negative v: uint-compare min (more-negative floats have larger uint bits)
    if (v >= 0.0f) atomicMax((int*)addr, __float_as_int(v));
    else           atomicMin((unsigned int*)addr, __float_as_uint(v));
}

__global__ void init_max_kernel(float* ws) {
    if (threadIdx.x < NM) ws[threadIdx.x] = -INFINITY;
}

__device__ __forceinline__ void load_weights(const float* __restrict__ wgt,
                                             const float* __restrict__ wf,
                                             float k[NM][9]) {
#pragma unroll
    for (int n = 0; n < NM; ++n) {
        float f = fminf(fmaxf(wf[n], 1.0f), 255.0f);          // clip(weight_factor, 1, 255)
#pragma unroll
        for (int j = 0; j < 9; ++j) {
            float w = fminf(fmaxf(wgt[n * 9 + j], -1.0f), 1.0f); // clip(weight, -1, 1)
            k[n][j] = w * f;
        }
    }
}

__device__ __forceinline__ void stage_tile(const float* __restrict__ img,
                                           float* tile, int t) {
    const float4* img4 = (const float4*)img;
#pragma unroll
    for (int i = 0; i < 4; ++i) {
        int idx = t + i * 256;       // float4 index 0..1023
        float4 v = img4[idx];
        int p = idx * 4;
        int h = p >> 6;
        int w = p & 63;
        float* dst = &tile[h * TPAD + w];
        dst[0] = v.x; dst[1] = v.y; dst[2] = v.z; dst[3] = v.w;
    }
}

// Load the 3x6 tap window (rows h-1..h+1, cols w0-1..w0+4) with zero padding.
__device__ __forceinline__ void load_taps(const float* tile, int h, int w0,
                                          float tap[3][6]) {
#pragma unroll
    for (int dy = -1; dy <= 1; ++dy) {
        int hh = h + dy;
        bool okh = (hh >= 0) && (hh < IMG);
#pragma unroll
        for (int dx = -1; dx <= 4; ++dx) {
            int ww = w0 + dx;
            bool ok = okh && (ww >= 0) && (ww < IMG);
            int idx = ok ? (hh * TPAD + ww) : 0;   // unconditional safe load + select
            float v = tile[idx];
            tap[dy + 1][dx + 1] = ok ? v : 0.0f;
        }
    }
}

__global__ __launch_bounds__(256) void conv_max_kernel(
        const float* __restrict__ in, const float* __restrict__ wgt,
        const float* __restrict__ wf, float* __restrict__ ws) {
    __shared__ float tile[IMG * TPAD];
    __shared__ float red[4][NM];
    const int c = blockIdx.x;
    const int t = threadIdx.x;
    const float* img = in + (size_t)c * HW;

    stage_tile(img, tile, t);
    float k[NM][9];
    load_weights(wgt, wf, k);
    __syncthreads();

    float m[NM] = {-INFINITY, -INFINITY, -INFINITY, -INFINITY};
#pragma unroll
    for (int g = 0; g < 4; ++g) {
        int pix = (t + g * 256) * 4;   // 4 consecutive pixels in one row
        int h = pix >> 6;
        int w0 = pix & 63;
        float tap[3][6];
        load_taps(tile, h, w0, tap);
#pragma unroll
        for (int i = 0; i < 4; ++i) {
#pragma unroll
            for (int n = 0; n < NM; ++n) {
                float acc = 0.0f;
#pragma unroll
                for (int dy = 0; dy < 3; ++dy)
#pragma unroll
                    for (int dx = 0; dx < 3; ++dx)
                        acc = fmaf(k[n][dy * 3 + dx], tap[dy][dx + i], acc);
                m[n] = fmaxf(m[n], acc);
            }
        }
    }

    // wave (64-lane) shuffle max reduce
#pragma unroll
    for (int off = 32; off >= 1; off >>= 1)
#pragma unroll
        for (int n = 0; n < NM; ++n)
            m[n] = fmaxf(m[n], __shfl_down(m[n], off, 64));

    const int wave = t >> 6, lane = t & 63;
    if (lane == 0)
#pragma unroll
        for (int n = 0; n < NM; ++n) red[wave][n] = m[n];
    __syncthreads();
    if (t == 0) {
#pragma unroll
        for (int n = 0; n < NM; ++n) {
            float v = fmaxf(fmaxf(red[0][n], red[1][n]), fmaxf(red[2][n], red[3][n]));
            atomicMaxF(&ws[n], v);
        }
    }
}

__global__ __launch_bounds__(256) void conv_out_kernel(
        const float* __restrict__ in, const float* __restrict__ wgt,
        const float* __restrict__ wf, const float* __restrict__ mx,
        float* __restrict__ out) {
    __shared__ float tile[IMG * TPAD];
    const int c = blockIdx.x;
    const int t = threadIdx.x;
    const float* img = in + (size_t)c * HW;

    stage_tile(img, tile, t);
    float k[NM][9];
    load_weights(wgt, wf, k);

    float inv[NM];
#pragma unroll
    for (int n = 0; n < NM; ++n) {
        float m = mx[n];
        float div = m * (1.0f / 128.0f);
        if (div > 0.0f) {
            float shift = rintf(log2f(div));   // round-half-even == jnp.round
            inv[n] = exp2f(-shift);            // exact power of 2
        } else {
            inv[n] = 1.0f;                     // where(div>0, shifted, result)
        }
    }
    __syncthreads();

#pragma unroll
    for (int g = 0; g < 4; ++g) {
        int pix = (t + g * 256) * 4;
        int h = pix >> 6;
        int w0 = pix & 63;
        float tap[3][6];
        load_taps(tile, h, w0, tap);
        float4 o[NM];
#pragma unroll
        for (int n = 0; n < NM; ++n) {
            float* op = (float*)&o[n];
#pragma unroll
            for (int i = 0; i < 4; ++i) {
                float acc = 0.0f;
#pragma unroll
                for (int dy = 0; dy < 3; ++dy)
#pragma unroll
                    for (int dx = 0; dx < 3; ++dx)
                        acc = fmaf(k[n][dy * 3 + dx], tap[dy][dx + i], acc);
                op[i] = tap[1][i + 1] + acc * inv[n];   // input + shifted conv
            }
        }
#pragma unroll
        for (int n = 0; n < NM; ++n) {
            size_t off = ((size_t)n * NCH + c) * HW + pix;
            *(float4*)(out + off) = o[n];
        }
    }
}

extern "C" void kernel_launch(void* const* d_in, const int* in_sizes, int n_in,
                              void* d_out, int out_size, void* d_ws, size_t ws_size,
                              hipStream_t stream) {
    const float* in  = (const float*)d_in[0];   // [1,4096,64,64]
    const float* wgt = (const float*)d_in[1];   // [4,9]
    const float* wf  = (const float*)d_in[2];   // [4,1]
    float* out = (float*)d_out;                 // [4,1,4096,64,64]
    float* ws  = (float*)d_ws;                  // 4 floats: per-n max

    init_max_kernel<<<dim3(1), dim3(64), 0, stream>>>(ws);
    conv_max_kernel<<<dim3(NCH), dim3(256), 0, stream>>>(in, wgt, wf, ws);
    conv_out_kernel<<<dim3(NCH), dim3(256), 0, stream>>>(in, wgt, wf, ws, out);
}

// Round 2
// 332.906 us; speedup vs baseline: 1.4869x; 1.4869x over previous
//
#include <hip/hip_runtime.h>
#include <math.h>

#define NCH 4096          // channel count (images)
#define IMG 64            // image side
#define HW  (IMG * IMG)   // 4096 pixels per image
#define NM  4             // number of multiplier kernels
#define TPAD 65           // LDS row stride: 65 -> stencil reads are 2-way bank aliasing (free)

// ws layout (floats): [0 .. NCH*NM) per-block partial maxima, [NCH*NM .. NCH*NM+NM) final maxima
#define WS_FINAL (NCH * NM)

__device__ __forceinline__ void load_weights(const float* __restrict__ wgt,
                                             const float* __restrict__ wf,
                                             float k[NM][9]) {
#pragma unroll
    for (int n = 0; n < NM; ++n) {
        float f = fminf(fmaxf(wf[n], 1.0f), 255.0f);          // clip(weight_factor, 1, 255)
#pragma unroll
        for (int j = 0; j < 9; ++j) {
            float w = fminf(fmaxf(wgt[n * 9 + j], -1.0f), 1.0f); // clip(weight, -1, 1)
            k[n][j] = w * f;
        }
    }
}

__device__ __forceinline__ void stage_tile(const float* __restrict__ img,
                                           float* tile, int t) {
    const float4* img4 = (const float4*)img;
#pragma unroll
    for (int i = 0; i < 4; ++i) {
        int idx = t + i * 256;       // float4 index 0..1023
        float4 v = img4[idx];
        int p = idx * 4;
        int h = p >> 6;
        int w = p & 63;
        float* dst = &tile[h * TPAD + w];
        dst[0] = v.x; dst[1] = v.y; dst[2] = v.z; dst[3] = v.w;
    }
}

// Load the 3x6 tap window (rows h-1..h+1, cols w0-1..w0+4) with zero padding.
__device__ __forceinline__ void load_taps(const float* tile, int h, int w0,
                                          float tap[3][6]) {
#pragma unroll
    for (int dy = -1; dy <= 1; ++dy) {
        int hh = h + dy;
        bool okh = (hh >= 0) && (hh < IMG);
#pragma unroll
        for (int dx = -1; dx <= 4; ++dx) {
            int ww = w0 + dx;
            bool ok = okh && (ww >= 0) && (ww < IMG);
            int idx = ok ? (hh * TPAD + ww) : 0;   // unconditional safe load + select
            float v = tile[idx];
            tap[dy + 1][dx + 1] = ok ? v : 0.0f;
        }
    }
}

__global__ __launch_bounds__(256) void conv_max_kernel(
        const float* __restrict__ in, const float* __restrict__ wgt,
        const float* __restrict__ wf, float* __restrict__ ws) {
    __shared__ float tile[IMG * TPAD];
    __shared__ float red[4][NM];
    const int c = blockIdx.x;
    const int t = threadIdx.x;
    const float* img = in + (size_t)c * HW;

    stage_tile(img, tile, t);
    float k[NM][9];
    load_weights(wgt, wf, k);
    __syncthreads();

    float m[NM] = {-INFINITY, -INFINITY, -INFINITY, -INFINITY};
#pragma unroll
    for (int g = 0; g < 4; ++g) {
        int pix = (t + g * 256) * 4;   // 4 consecutive pixels in one row
        int h = pix >> 6;
        int w0 = pix & 63;
        float tap[3][6];
        load_taps(tile, h, w0, tap);
#pragma unroll
        for (int i = 0; i < 4; ++i) {
#pragma unroll
            for (int n = 0; n < NM; ++n) {
                float acc = 0.0f;
#pragma unroll
                for (int dy = 0; dy < 3; ++dy)
#pragma unroll
                    for (int dx = 0; dx < 3; ++dx)
                        acc = fmaf(k[n][dy * 3 + dx], tap[dy][dx + i], acc);
                m[n] = fmaxf(m[n], acc);
            }
        }
    }

    // wave (64-lane) shuffle max reduce
#pragma unroll
    for (int off = 32; off >= 1; off >>= 1)
#pragma unroll
        for (int n = 0; n < NM; ++n)
            m[n] = fmaxf(m[n], __shfl_down(m[n], off, 64));

    const int wave = t >> 6, lane = t & 63;
    if (lane == 0)
#pragma unroll
        for (int n = 0; n < NM; ++n) red[wave][n] = m[n];
    __syncthreads();
    if (t == 0) {
        // NO atomics: every block owns its private slot. 16K same-address
        // atomics cost ~200 us of L2 serialization in R0 -> replaced by a
        // contention-free store + tiny tree-reduce kernel.
        float4 v;
        v.x = fmaxf(fmaxf(red[0][0], red[1][0]), fmaxf(red[2][0], red[3][0]));
        v.y = fmaxf(fmaxf(red[0][1], red[1][1]), fmaxf(red[2][1], red[3][1]));
        v.z = fmaxf(fmaxf(red[0][2], red[1][2]), fmaxf(red[2][2], red[3][2]));
        v.w = fmaxf(fmaxf(red[0][3], red[1][3]), fmaxf(red[2][3], red[3][3]));
        *(float4*)(ws + (size_t)c * NM) = v;
    }
}

__global__ __launch_bounds__(256) void reduce_max_kernel(float* __restrict__ ws) {
    __shared__ float red[4][NM];
    const int t = threadIdx.x;
    const float4* p4 = (const float4*)ws;   // 4096 partial float4s
    float4 m = {-INFINITY, -INFINITY, -INFINITY, -INFINITY};
#pragma unroll
    for (int i = 0; i < NCH / 256; ++i) {
        float4 v = p4[t + i * 256];
        m.x = fmaxf(m.x, v.x); m.y = fmaxf(m.y, v.y);
        m.z = fmaxf(m.z, v.z); m.w = fmaxf(m.w, v.w);
    }
#pragma unroll
    for (int off = 32; off >= 1; off >>= 1) {
        m.x = fmaxf(m.x, __shfl_down(m.x, off, 64));
        m.y = fmaxf(m.y, __shfl_down(m.y, off, 64));
        m.z = fmaxf(m.z, __shfl_down(m.z, off, 64));
        m.w = fmaxf(m.w, __shfl_down(m.w, off, 64));
    }
    const int wave = t >> 6, lane = t & 63;
    if (lane == 0) {
        red[wave][0] = m.x; red[wave][1] = m.y;
        red[wave][2] = m.z; red[wave][3] = m.w;
    }
    __syncthreads();
    if (t == 0) {
        float4 v;
        v.x = fmaxf(fmaxf(red[0][0], red[1][0]), fmaxf(red[2][0], red[3][0]));
        v.y = fmaxf(fmaxf(red[0][1], red[1][1]), fmaxf(red[2][1], red[3][1]));
        v.z = fmaxf(fmaxf(red[0][2], red[1][2]), fmaxf(red[2][2], red[3][2]));
        v.w = fmaxf(fmaxf(red[0][3], red[1][3]), fmaxf(red[2][3], red[3][3]));
        *(float4*)(ws + WS_FINAL) = v;
    }
}

__global__ __launch_bounds__(256) void conv_out_kernel(
        const float* __restrict__ in, const float* __restrict__ wgt,
        const float* __restrict__ wf, const float* __restrict__ mx,
        float* __restrict__ out) {
    __shared__ float tile[IMG * TPAD];
    const int c = blockIdx.x;
    const int t = threadIdx.x;
    const float* img = in + (size_t)c * HW;

    stage_tile(img, tile, t);
    float k[NM][9];
    load_weights(wgt, wf, k);

    float inv[NM];
#pragma unroll
    for (int n = 0; n < NM; ++n) {
        float m = mx[n];
        float div = m * (1.0f / 128.0f);
        if (div > 0.0f) {
            float shift = rintf(log2f(div));   // round-half-even == jnp.round
            inv[n] = exp2f(-shift);            // exact power of 2
        } else {
            inv[n] = 1.0f;                     // where(div>0, shifted, result)
        }
    }
    __syncthreads();

#pragma unroll
    for (int g = 0; g < 4; ++g) {
        int pix = (t + g * 256) * 4;
        int h = pix >> 6;
        int w0 = pix & 63;
        float tap[3][6];
        load_taps(tile, h, w0, tap);
        float4 o[NM];
#pragma unroll
        for (int n = 0; n < NM; ++n) {
            float* op = (float*)&o[n];
#pragma unroll
            for (int i = 0; i < 4; ++i) {
                float acc = 0.0f;
#pragma unroll
                for (int dy = 0; dy < 3; ++dy)
#pragma unroll
                    for (int dx = 0; dx < 3; ++dx)
                        acc = fmaf(k[n][dy * 3 + dx], tap[dy][dx + i], acc);
                op[i] = tap[1][i + 1] + acc * inv[n];   // input + shifted conv
            }
        }
#pragma unroll
        for (int n = 0; n < NM; ++n) {
            size_t off = ((size_t)n * NCH + c) * HW + pix;
            *(float4*)(out + off) = o[n];
        }
    }
}

extern "C" void kernel_launch(void* const* d_in, const int* in_sizes, int n_in,
                              void* d_out, int out_size, void* d_ws, size_t ws_size,
                              hipStream_t stream) {
    const float* in  = (const float*)d_in[0];   // [1,4096,64,64]
    const float* wgt = (const float*)d_in[1];   // [4,9]
    const float* wf  = (const float*)d_in[2];   // [4,1]
    float* out = (float*)d_out;                 // [4,1,4096,64,64]
    float* ws  = (float*)d_ws;                  // partial maxima + finals

    conv_max_kernel<<<dim3(NCH), dim3(256), 0, stream>>>(in, wgt, wf, ws);
    reduce_max_kernel<<<dim3(1), dim3(256), 0, stream>>>(ws);
    conv_out_kernel<<<dim3(NCH), dim3(256), 0, stream>>>(in, wgt, wf, ws + WS_FINAL, out);
}